// Round 13
// baseline (592.091 us; speedup 1.0000x reference)
//
#include <hip/hip_runtime.h>
#include <cstddef>

#define NCF 10

struct TFKeys { unsigned k[2 * NCF]; };

typedef __attribute__((ext_vector_type(8))) _Float16 f16x8;
typedef __attribute__((ext_vector_type(4))) float f32x4;

// Threefry-2x32, 20 rounds (JAX-compatible, partitionable semantics verified R1).
__host__ __device__ __forceinline__ void tf2x32(unsigned k0, unsigned k1,
                                                unsigned x0, unsigned x1,
                                                unsigned& o0, unsigned& o1) {
  const unsigned ks2 = k0 ^ k1 ^ 0x1BD11BDAu;
  x0 += k0; x1 += k1;
#define TF_R(r) x0 += x1; x1 = (x1 << (r)) | (x1 >> (32 - (r))); x1 ^= x0;
  TF_R(13) TF_R(15) TF_R(26) TF_R(6)
  x0 += k1;  x1 += ks2 + 1u;
  TF_R(17) TF_R(29) TF_R(16) TF_R(24)
  x0 += ks2; x1 += k0 + 2u;
  TF_R(13) TF_R(15) TF_R(26) TF_R(6)
  x0 += k0;  x1 += k1 + 3u;
  TF_R(17) TF_R(29) TF_R(16) TF_R(24)
  x0 += k1;  x1 += ks2 + 4u;
  TF_R(13) TF_R(15) TF_R(26) TF_R(6)
  x0 += ks2; x1 += k0 + 5u;
#undef TF_R
  o0 = x0; o1 = x1;
}

__device__ __forceinline__ float u01(unsigned bits) {
  return __uint_as_float((bits >> 9) | 0x3f800000u) - 1.0f;
}

// fp16x3 split of 8 floats: x = hi + lo, |x - hi - lo| <= 2^-24 |x|.
__device__ __forceinline__ void split44(const float4 a, const float4 b,
                                        f16x8& hh, f16x8& ll) {
  const float v[8] = {a.x, a.y, a.z, a.w, b.x, b.y, b.z, b.w};
#pragma unroll
  for (int e = 0; e < 8; ++e) {
    const _Float16 h = (_Float16)v[e];
    hh[e] = h;
    ll[e] = (_Float16)(v[e] - (float)h);
  }
}

// D += Ah*Bh + Ah*Bl + Al*Bh  (drops Al*Bl ~ 2^-24). A = activations, B = W.
#define MFMA3(acc, ah, al, bh, bl)                                          \
  acc = __builtin_amdgcn_mfma_f32_16x16x32_f16(ah, bh, acc, 0, 0, 0);       \
  acc = __builtin_amdgcn_mfma_f32_16x16x32_f16(ah, bl, acc, 0, 0, 0);       \
  acc = __builtin_amdgcn_mfma_f32_16x16x32_f16(al, bh, acc, 0, 0, 0);

// Stage W[K][N] (row-major f32) into hi/lo B-fragment layout (verified R2):
// frag elem ((kt*NTN+nt)*64+lane)*8+e <-> W[kt*32+(lane>>4)*8+e][nt*16+(lane&15)]
template <int K, int N>
__device__ __forceinline__ void stage_frags(const float* __restrict__ W,
                                            _Float16* fh, _Float16* fl, int t) {
  constexpr int NTN = N / 16;
  for (int i = t; i < K * N; i += 512) {
    const int e = i & 7, lane = (i >> 3) & 63, tile = i >> 9;
    const int kt = tile / NTN, nt = tile % NTN;
    const int k = kt * 32 + ((lane >> 4) << 3) + e;
    const int c = nt * 16 + (lane & 15);
    const float w = W[k * N + c];
    const _Float16 h = (_Float16)w;
    fh[i] = h;
    fl[i] = (_Float16)(w - (float)h);
  }
}

// [32][32] chunk buffer, XOR-swizzled (R4-verified pattern): writes/reads are
// <=2-way bank conflicts (free per m136).
__device__ __forceinline__ int swz(int row, int col) {
  return (row << 5) + (col ^ ((row & 7) << 2));
}

// ---------------------------------------------------------------------------
// Fused kernel, R12 structure (32 samples/wave, two 16-row A-tiles, 447us)
// + RNG SOFTWARE PIPELINE: pass p+1's threefry fragments are generated in the
// same scheduling region as pass p's MFMA body (fully independent), so the
// ~2400-instr pure-VALU RNG burst hides under the MFMA shadow instead of
// serializing with it (R12: VALUBusy 59 + MfmaUtil 21 = phase-aligned pipes).
// Ping-pong frag sets aA/aB, statically indexed; pacc accumulation order is
// unchanged (p=0..10) -> numerics bit-identical to R12 (absmax 4.77e-7).
// __launch_bounds__(512,1) -> 2 waves/EU, accumulators ride in AGPRs
// (R12: VGPR 128, zero spills). pw parked in d_ws. LDS 112KB, no barriers /
// no global loads in the pass loop.
// ---------------------------------------------------------------------------
__global__ __launch_bounds__(512, 1)
void infl_fused(const float* __restrict__ obs, const float* __restrict__ actions,
                const float* __restrict__ W1, const float* __restrict__ b1,
                const float* __restrict__ W2, const float* __restrict__ b2,
                const float* __restrict__ W3, const float* __restrict__ b3,
                float* __restrict__ pwbuf, float* __restrict__ out, TFKeys keys) {
  // Prologue: [0,65536) = W1-obs half frags. Pass loop: [0,81920) weight
  // frags; [81920,114688) = 8 x 4KB per-wave [32][32] chunk buffers.
  __shared__ __align__(16) unsigned char smem[114688];
  _Float16* w1oh = (_Float16*)smem;
  _Float16* w1ol = (_Float16*)(smem + 32768);
  _Float16* w1h  = (_Float16*)smem;
  _Float16* w1l  = (_Float16*)(smem + 16384);
  _Float16* w2h  = (_Float16*)(smem + 32768);
  _Float16* w2l  = (_Float16*)(smem + 49152);
  _Float16* w3h  = (_Float16*)(smem + 65536);
  _Float16* w3l  = (_Float16*)(smem + 73728);

  const int t = threadIdx.x, wave = t >> 6, lane = t & 63;
  const int R0 = blockIdx.x * 256 + wave * 32;   // wave owns 32 samples
  const int cA = lane & 15;            // A-row within tile (sample)
  const int kg = (lane >> 4) << 3;     // k base within 32-k tile
  const int r0 = (lane >> 4) << 2;     // C/D row base
  float* cb = (float*)(smem + 81920 + wave * 4096);

  // ========== prologue: ho[g] = b1 + obs @ W1[0:256] for both tiles =======
  f32x4 ho[2][8];
#pragma unroll
  for (int nt = 0; nt < 8; ++nt) {
    const float bv = b1[nt * 16 + cA];
    ho[0][nt] = (f32x4){bv, bv, bv, bv};
    ho[1][nt] = ho[0][nt];
  }
  {
    const float* orow0 = obs + (size_t)(R0 + cA) * 256;
    const float* orow1 = obs + (size_t)(R0 + 16 + cA) * 256;
    for (int half = 0; half < 2; ++half) {
      __syncthreads();   // previous half's MFMAs done reading frags
      stage_frags<128, 128>(W1 + half * 128 * 128, w1oh, w1ol, t);
      __syncthreads();
#pragma unroll
      for (int kt = 0; kt < 4; ++kt) {
        f16x8 oh0, ol0, oh1, ol1;
        {
          const float4 va = *(const float4*)(orow0 + half * 128 + kt * 32 + kg);
          const float4 vb = *(const float4*)(orow0 + half * 128 + kt * 32 + kg + 4);
          split44(va, vb, oh0, ol0);
          const float4 vc = *(const float4*)(orow1 + half * 128 + kt * 32 + kg);
          const float4 vd = *(const float4*)(orow1 + half * 128 + kt * 32 + kg + 4);
          split44(vc, vd, oh1, ol1);
        }
#pragma unroll
        for (int nt = 0; nt < 8; ++nt) {
          const int tile = kt * 8 + nt;
          const f16x8 bh = *(const f16x8*)&w1oh[(tile * 64 + lane) * 8];
          const f16x8 bl = *(const f16x8*)&w1ol[(tile * 64 + lane) * 8];
          MFMA3(ho[0][nt], oh0, ol0, bh, bl)
          MFMA3(ho[1][nt], oh1, ol1, bh, bl)
        }
      }
    }
  }
  __syncthreads();   // prologue reads done; restage pass weights

  stage_frags<64, 128>(W1 + 256 * 128, w1h, w1l, t);
  stage_frags<128, 64>(W2, w2h, w2l, t);
  stage_frags<64, 64>(W3, w3h, w3l, t);

  float b2r[4];
#pragma unroll
  for (int n2 = 0; n2 < 4; ++n2) b2r[n2] = b2[n2 * 16 + cA];
  __syncthreads();   // last barrier of the kernel

  // ============== MLP body (one pass), 2 sample-tiles per wave ============
#define MLP_BODY(AH, AL, HAS_ACT, acc3)                                      \
  {                                                                          \
    f32x4 a2[2][4];                                                          \
    _Pragma("unroll") for (int g = 0; g < 2; ++g)                            \
      _Pragma("unroll") for (int n2 = 0; n2 < 4; ++n2)                       \
        a2[g][n2] = (f32x4){b2r[n2], b2r[n2], b2r[n2], b2r[n2]};             \
    _Pragma("unroll") for (int c = 0; c < 4; ++c) {                          \
      f32x4 a10 = ho[0][2 * c], a11 = ho[0][2 * c + 1];                      \
      f32x4 a12 = ho[1][2 * c], a13 = ho[1][2 * c + 1];                      \
      if (HAS_ACT) {                                                         \
        _Pragma("unroll") for (int kt = 0; kt < 2; ++kt) {                   \
          const int t0 = ((kt * 8 + 2 * c) * 64 + lane) * 8;                 \
          const int t1 = ((kt * 8 + 2 * c + 1) * 64 + lane) * 8;             \
          const f16x8 bh0 = *(const f16x8*)&w1h[t0];                         \
          const f16x8 bl0 = *(const f16x8*)&w1l[t0];                         \
          MFMA3(a10, AH[0][kt], AL[0][kt], bh0, bl0)                         \
          MFMA3(a12, AH[1][kt], AL[1][kt], bh0, bl0)                         \
          const f16x8 bh1 = *(const f16x8*)&w1h[t1];                         \
          const f16x8 bl1 = *(const f16x8*)&w1l[t1];                         \
          MFMA3(a11, AH[0][kt], AL[0][kt], bh1, bl1)                         \
          MFMA3(a13, AH[1][kt], AL[1][kt], bh1, bl1)                         \
        }                                                                    \
      }                                                                      \
      _Pragma("unroll") for (int j = 0; j < 4; ++j) {                        \
        cb[swz(r0 + j, cA)]           = fmaxf(a10[j], 0.f);                  \
        cb[swz(r0 + j, 16 + cA)]      = fmaxf(a11[j], 0.f);                  \
        cb[swz(16 + r0 + j, cA)]      = fmaxf(a12[j], 0.f);                  \
        cb[swz(16 + r0 + j, 16 + cA)] = fmaxf(a13[j], 0.f);                  \
      }                                                                      \
      f16x8 hh0, hl0, hh1, hl1;                                              \
      {                                                                      \
        const float4 va = *(const float4*)&cb[swz(cA, kg)];                  \
        const float4 vb = *(const float4*)&cb[swz(cA, kg + 4)];              \
        split44(va, vb, hh0, hl0);                                           \
        const float4 vc = *(const float4*)&cb[swz(16 + cA, kg)];             \
        const float4 vd = *(const float4*)&cb[swz(16 + cA, kg + 4)];         \
        split44(vc, vd, hh1, hl1);                                           \
      }                                                                      \
      _Pragma("unroll") for (int n2 = 0; n2 < 4; ++n2) {                     \
        const int tt = ((c * 4 + n2) * 64 + lane) * 8;                       \
        const f16x8 wh = *(const f16x8*)&w2h[tt];                            \
        const f16x8 wl = *(const f16x8*)&w2l[tt];                            \
        MFMA3(a2[0][n2], hh0, hl0, wh, wl)                                   \
        MFMA3(a2[1][n2], hh1, hl1, wh, wl)                                   \
      }                                                                      \
    }                                                                        \
    _Pragma("unroll") for (int d = 0; d < 2; ++d) {                          \
      _Pragma("unroll") for (int j = 0; j < 4; ++j) {                        \
        cb[swz(r0 + j, cA)]           = fmaxf(a2[0][2 * d][j], 0.f);         \
        cb[swz(r0 + j, 16 + cA)]      = fmaxf(a2[0][2 * d + 1][j], 0.f);     \
        cb[swz(16 + r0 + j, cA)]      = fmaxf(a2[1][2 * d][j], 0.f);         \
        cb[swz(16 + r0 + j, 16 + cA)] = fmaxf(a2[1][2 * d + 1][j], 0.f);     \
      }                                                                      \
      f16x8 hh0, hl0, hh1, hl1;                                              \
      {                                                                      \
        const float4 va = *(const float4*)&cb[swz(cA, kg)];                  \
        const float4 vb = *(const float4*)&cb[swz(cA, kg + 4)];              \
        split44(va, vb, hh0, hl0);                                           \
        const float4 vc = *(const float4*)&cb[swz(16 + cA, kg)];             \
        const float4 vd = *(const float4*)&cb[swz(16 + cA, kg + 4)];         \
        split44(vc, vd, hh1, hl1);                                           \
      }                                                                      \
      _Pragma("unroll") for (int n3 = 0; n3 < 4; ++n3) {                     \
        const int tt = ((d * 4 + n3) * 64 + lane) * 8;                       \
        const f16x8 wh = *(const f16x8*)&w3h[tt];                            \
        const f16x8 wl = *(const f16x8*)&w3l[tt];                            \
        MFMA3(acc3[0][n3], hh0, hl0, wh, wl)                                 \
        MFMA3(acc3[1][n3], hh1, hl1, wh, wl)                                 \
      }                                                                      \
    }                                                                        \
  }

  // RNG fragment generation for pass PP into frag set (AH, AL).
#define GEN_RNG(PP, AH, AL)                                                  \
  {                                                                          \
    const unsigned gk0 = keys.k[2 * ((PP) - 1)];                             \
    const unsigned gk1 = keys.k[2 * ((PP) - 1) + 1];                         \
    _Pragma("unroll") for (int g = 0; g < 2; ++g) {                          \
      const unsigned base = (unsigned)(R0 + g * 16 + cA) * 64u + (unsigned)kg;\
      _Pragma("unroll") for (int kt = 0; kt < 2; ++kt) {                     \
        float v[8];                                                          \
        _Pragma("unroll") for (int e = 0; e < 8; ++e) {                      \
          unsigned o0, o1;                                                   \
          tf2x32(gk0, gk1, 0u, base + (unsigned)(kt * 32 + e), o0, o1);      \
          v[e] = u01(o0 ^ o1);                                               \
        }                                                                    \
        split44(*(const float4*)&v[0], *(const float4*)&v[4],                \
                AH[g][kt], AL[g][kt]);                                       \
      }                                                                      \
    }                                                                        \
  }

  f16x8 aA[2][2], lA[2][2], aB[2][2], lB[2][2];

  // ---- with-actions pass FIRST -> pw -> parked in pwbuf (d_ws) ----
  {
#pragma unroll
    for (int g = 0; g < 2; ++g) {
      const float* arow = actions + (size_t)(R0 + g * 16 + cA) * 64 + kg;
#pragma unroll
      for (int kt = 0; kt < 2; ++kt) {
        const float4 va = *(const float4*)(arow + kt * 32);
        const float4 vb = *(const float4*)(arow + kt * 32 + 4);
        split44(va, vb, aA[g][kt], lA[g][kt]);
      }
    }
    f32x4 pw[2][4];
#pragma unroll
    for (int g = 0; g < 2; ++g)
#pragma unroll
      for (int nt = 0; nt < 4; ++nt) pw[g][nt] = (f32x4){0.f, 0.f, 0.f, 0.f};
    MLP_BODY(aA, lA, true, pw)
#pragma unroll
    for (int g = 0; g < 2; ++g)
#pragma unroll
      for (int n3 = 0; n3 < 4; ++n3)
#pragma unroll
        for (int j = 0; j < 4; ++j)
          pwbuf[(size_t)(R0 + g * 16 + r0 + j) * 64 + n3 * 16 + cA] =
              pw[g][n3][j];
  }

  // ---- passes 0..10 -> pacc, RNG pipelined one pass ahead ----
  f32x4 pacc[2][4];
#pragma unroll
  for (int g = 0; g < 2; ++g)
#pragma unroll
    for (int nt = 0; nt < 4; ++nt) pacc[g][nt] = (f32x4){0.f, 0.f, 0.f, 0.f};

  // pass 0 (zero actions) overlapped with RNG for pass 1
  GEN_RNG(1, aA, lA)
  MLP_BODY(aA, lA, false, pacc)      // HAS_ACT=false: aA untouched

  for (int i = 0; i < 4; ++i) {      // pass pairs (1,2),(3,4),(5,6),(7,8)
    GEN_RNG(2 * i + 2, aB, lB)       // next-pass RNG interleaves with...
    MLP_BODY(aA, lA, true, pacc)     // ...current pass's MFMA body
    GEN_RNG(2 * i + 3, aA, lA)
    MLP_BODY(aB, lB, true, pacc)
  }
  GEN_RNG(10, aB, lB)
  MLP_BODY(aA, lA, true, pacc)       // pass 9
  MLP_BODY(aB, lB, true, pacc)       // pass 10

  // ---- epilogue: reload pw; softmax/KL per row, 16-lane shfl reductions ----
  const float inv11 = 1.0f / 11.0f;
  float b3r[4];
#pragma unroll
  for (int n3 = 0; n3 < 4; ++n3) b3r[n3] = b3[n3 * 16 + cA];

#pragma unroll
  for (int g = 0; g < 2; ++g) {
#pragma unroll
    for (int j = 0; j < 4; ++j) {
      float pwv[4], pav[4];
#pragma unroll
      for (int nt = 0; nt < 4; ++nt) {
        pwv[nt] = pwbuf[(size_t)(R0 + g * 16 + r0 + j) * 64 + nt * 16 + cA] +
                  b3r[nt];
        pav[nt] = pacc[g][nt][j] * inv11 + b3r[nt];
      }
      float mw = fmaxf(fmaxf(pwv[0], pwv[1]), fmaxf(pwv[2], pwv[3]));
      float ma = fmaxf(fmaxf(pav[0], pav[1]), fmaxf(pav[2], pav[3]));
#pragma unroll
      for (int off = 1; off < 16; off <<= 1) {
        mw = fmaxf(mw, __shfl_xor(mw, off, 64));
        ma = fmaxf(ma, __shfl_xor(ma, off, 64));
      }
      float sw = 0.f, sa = 0.f;
#pragma unroll
      for (int nt = 0; nt < 4; ++nt) {
        sw += expf(pwv[nt] - mw);
        sa += expf(pav[nt] - ma);
      }
#pragma unroll
      for (int off = 1; off < 16; off <<= 1) {
        sw += __shfl_xor(sw, off, 64);
        sa += __shfl_xor(sa, off, 64);
      }
      const float lzw = logf(sw), lza = logf(sa);
      float contrib = 0.f;
#pragma unroll
      for (int nt = 0; nt < 4; ++nt) {
        const float lq = pav[nt] - ma - lza;
        const float lp = pwv[nt] - mw - lzw;
        contrib += expf(lq) * (lq - lp);
      }
#pragma unroll
      for (int off = 1; off < 16; off <<= 1)
        contrib += __shfl_xor(contrib, off, 64);
      if (cA == 0) out[R0 + g * 16 + r0 + j] = contrib * (1.0f / 64.0f);
    }
  }
}

extern "C" void kernel_launch(void* const* d_in, const int* in_sizes, int n_in,
                              void* d_out, int out_size, void* d_ws, size_t ws_size,
                              hipStream_t stream) {
  (void)in_sizes; (void)n_in; (void)ws_size; (void)out_size;
  const float* obs     = (const float*)d_in[0];
  const float* actions = (const float*)d_in[1];
  const float* W1      = (const float*)d_in[2];
  const float* b1      = (const float*)d_in[3];
  const float* W2      = (const float*)d_in[4];
  const float* b2      = (const float*)d_in[5];
  const float* W3      = (const float*)d_in[6];
  const float* b3      = (const float*)d_in[7];

  float* pwbuf = (float*)d_ws;   // 131072 x 64 f32 = 33.5 MB

  TFKeys keys;
  for (unsigned j = 0; j < NCF; ++j) {
    unsigned o0, o1;
    tf2x32(0u, 42u, 0u, j, o0, o1);
    keys.k[2 * j]     = o0;
    keys.k[2 * j + 1] = o1;
  }

  hipLaunchKernelGGL(infl_fused, dim3(512), dim3(512), 0, stream,
                     obs, actions, W1, b1, W2, b2, W3, b3, pwbuf,
                     (float*)d_out, keys);
}

// Round 14
// 579.192 us; speedup vs baseline: 1.0223x; 1.0223x over previous
//
#include <hip/hip_runtime.h>
#include <cstddef>

#define NCF 10

struct TFKeys { unsigned k[2 * NCF]; };

typedef __attribute__((ext_vector_type(8))) _Float16 f16x8;
typedef __attribute__((ext_vector_type(4))) float f32x4;

// Threefry-2x32, 20 rounds (JAX-compatible, partitionable semantics verified R1).
__host__ __device__ __forceinline__ void tf2x32(unsigned k0, unsigned k1,
                                                unsigned x0, unsigned x1,
                                                unsigned& o0, unsigned& o1) {
  const unsigned ks2 = k0 ^ k1 ^ 0x1BD11BDAu;
  x0 += k0; x1 += k1;
#define TF_R(r) x0 += x1; x1 = (x1 << (r)) | (x1 >> (32 - (r))); x1 ^= x0;
  TF_R(13) TF_R(15) TF_R(26) TF_R(6)
  x0 += k1;  x1 += ks2 + 1u;
  TF_R(17) TF_R(29) TF_R(16) TF_R(24)
  x0 += ks2; x1 += k0 + 2u;
  TF_R(13) TF_R(15) TF_R(26) TF_R(6)
  x0 += k0;  x1 += k1 + 3u;
  TF_R(17) TF_R(29) TF_R(16) TF_R(24)
  x0 += k1;  x1 += ks2 + 4u;
  TF_R(13) TF_R(15) TF_R(26) TF_R(6)
  x0 += ks2; x1 += k0 + 5u;
#undef TF_R
  o0 = x0; o1 = x1;
}

__device__ __forceinline__ float u01(unsigned bits) {
  return __uint_as_float((bits >> 9) | 0x3f800000u) - 1.0f;
}

// fp16x3 split of 8 floats: x = hi + lo, |x - hi - lo| <= 2^-24 |x|.
__device__ __forceinline__ void split44(const float4 a, const float4 b,
                                        f16x8& hh, f16x8& ll) {
  const float v[8] = {a.x, a.y, a.z, a.w, b.x, b.y, b.z, b.w};
#pragma unroll
  for (int e = 0; e < 8; ++e) {
    const _Float16 h = (_Float16)v[e];
    hh[e] = h;
    ll[e] = (_Float16)(v[e] - (float)h);
  }
}

// D += Ah*Bh + Ah*Bl + Al*Bh  (drops Al*Bl ~ 2^-24). A = activations, B = W.
#define MFMA3(acc, ah, al, bh, bl)                                          \
  acc = __builtin_amdgcn_mfma_f32_16x16x32_f16(ah, bh, acc, 0, 0, 0);       \
  acc = __builtin_amdgcn_mfma_f32_16x16x32_f16(ah, bl, acc, 0, 0, 0);       \
  acc = __builtin_amdgcn_mfma_f32_16x16x32_f16(al, bh, acc, 0, 0, 0);

// Stage W[K][N] (row-major f32) into hi/lo B-fragment layout (verified R2):
// frag elem ((kt*NTN+nt)*64+lane)*8+e <-> W[kt*32+(lane>>4)*8+e][nt*16+(lane&15)]
template <int K, int N>
__device__ __forceinline__ void stage_frags(const float* __restrict__ W,
                                            _Float16* fh, _Float16* fl, int t) {
  constexpr int NTN = N / 16;
  for (int i = t; i < K * N; i += 512) {
    const int e = i & 7, lane = (i >> 3) & 63, tile = i >> 9;
    const int kt = tile / NTN, nt = tile % NTN;
    const int k = kt * 32 + ((lane >> 4) << 3) + e;
    const int c = nt * 16 + (lane & 15);
    const float w = W[k * N + c];
    const _Float16 h = (_Float16)w;
    fh[i] = h;
    fl[i] = (_Float16)(w - (float)h);
  }
}

// [32][32] chunk buffer, XOR-swizzled (R4-verified pattern): writes/reads are
// <=2-way bank conflicts (free per m136).
__device__ __forceinline__ int swz(int row, int col) {
  return (row << 5) + (col ^ ((row & 7) << 2));
}

// ---------------------------------------------------------------------------
// Fused kernel = R12 (32 samples/wave, 447us, zero spills) + two
// register-neutral latency fixes (R13's 2-set pipeline spilled: VGPR cap is
// hard 65536/threads = 128 @512thr; launch-bounds 2nd arg & waves_per_eu are
// IGNORED by this toolchain — model fitted over R3..R13):
//  (1) single-set RNG reorder: GEN(1) hoisted above pass 0; GEN(p+1) placed
//      AFTER body(p). Frags are only read in body's L1 phase, so the
//      scheduler can float GEN's ~2400 VALU ops into body(p)'s L2/H2/L3
//      MFMA shadow (WAR freed by SSA renaming). No extra frag registers.
//  (2) dual cb buffers (cb0/cb1, 8KB/wave, LDS 144KB): consume chunk c-1
//      after producing chunk c, hiding the LDS store->load round-trip under
//      the next chunk's L1 MFMAs. Chunk consumption order unchanged ->
//      pacc accumulation bit-identical (absmax 4.768e-7 lineage).
// pw parked in d_ws; no barriers / no global loads in the pass loop.
// ---------------------------------------------------------------------------
__global__ __launch_bounds__(512, 1)
void infl_fused(const float* __restrict__ obs, const float* __restrict__ actions,
                const float* __restrict__ W1, const float* __restrict__ b1,
                const float* __restrict__ W2, const float* __restrict__ b2,
                const float* __restrict__ W3, const float* __restrict__ b3,
                float* __restrict__ pwbuf, float* __restrict__ out, TFKeys keys) {
  // Prologue: [0,65536) = W1-obs half frags. Pass loop: [0,81920) weight
  // frags; [81920,147456) = 8 waves x 2 x 4KB chunk buffers.
  __shared__ __align__(16) unsigned char smem[147456];
  _Float16* w1oh = (_Float16*)smem;
  _Float16* w1ol = (_Float16*)(smem + 32768);
  _Float16* w1h  = (_Float16*)smem;
  _Float16* w1l  = (_Float16*)(smem + 16384);
  _Float16* w2h  = (_Float16*)(smem + 32768);
  _Float16* w2l  = (_Float16*)(smem + 49152);
  _Float16* w3h  = (_Float16*)(smem + 65536);
  _Float16* w3l  = (_Float16*)(smem + 73728);

  const int t = threadIdx.x, wave = t >> 6, lane = t & 63;
  const int R0 = blockIdx.x * 256 + wave * 32;   // wave owns 32 samples
  const int cA = lane & 15;            // A-row within tile (sample)
  const int kg = (lane >> 4) << 3;     // k base within 32-k tile
  const int r0 = (lane >> 4) << 2;     // C/D row base
  float* cb0 = (float*)(smem + 81920 + wave * 8192);
  float* cb1 = cb0 + 1024;

  // ========== prologue: ho[g] = b1 + obs @ W1[0:256] for both tiles =======
  f32x4 ho[2][8];
#pragma unroll
  for (int nt = 0; nt < 8; ++nt) {
    const float bv = b1[nt * 16 + cA];
    ho[0][nt] = (f32x4){bv, bv, bv, bv};
    ho[1][nt] = ho[0][nt];
  }
  {
    const float* orow0 = obs + (size_t)(R0 + cA) * 256;
    const float* orow1 = obs + (size_t)(R0 + 16 + cA) * 256;
    for (int half = 0; half < 2; ++half) {
      __syncthreads();   // previous half's MFMAs done reading frags
      stage_frags<128, 128>(W1 + half * 128 * 128, w1oh, w1ol, t);
      __syncthreads();
#pragma unroll
      for (int kt = 0; kt < 4; ++kt) {
        f16x8 oh0, ol0, oh1, ol1;
        {
          const float4 va = *(const float4*)(orow0 + half * 128 + kt * 32 + kg);
          const float4 vb = *(const float4*)(orow0 + half * 128 + kt * 32 + kg + 4);
          split44(va, vb, oh0, ol0);
          const float4 vc = *(const float4*)(orow1 + half * 128 + kt * 32 + kg);
          const float4 vd = *(const float4*)(orow1 + half * 128 + kt * 32 + kg + 4);
          split44(vc, vd, oh1, ol1);
        }
#pragma unroll
        for (int nt = 0; nt < 8; ++nt) {
          const int tile = kt * 8 + nt;
          const f16x8 bh = *(const f16x8*)&w1oh[(tile * 64 + lane) * 8];
          const f16x8 bl = *(const f16x8*)&w1ol[(tile * 64 + lane) * 8];
          MFMA3(ho[0][nt], oh0, ol0, bh, bl)
          MFMA3(ho[1][nt], oh1, ol1, bh, bl)
        }
      }
    }
  }
  __syncthreads();   // prologue reads done; restage pass weights

  stage_frags<64, 128>(W1 + 256 * 128, w1h, w1l, t);
  stage_frags<128, 64>(W2, w2h, w2l, t);
  stage_frags<64, 64>(W3, w3h, w3l, t);

  float b2r[4];
#pragma unroll
  for (int n2 = 0; n2 < 4; ++n2) b2r[n2] = b2[n2 * 16 + cA];
  __syncthreads();   // last barrier of the kernel

  // ======================= per-phase helpers ==============================
  // L1 chunk C -> BUF (produce); L2 consumes BUF with weight slab C.
#define L1_PRODUCE(C, BUF, AH, AL, HAS_ACT)                                  \
  {                                                                          \
    f32x4 a10 = ho[0][2 * (C)], a11 = ho[0][2 * (C) + 1];                    \
    f32x4 a12 = ho[1][2 * (C)], a13 = ho[1][2 * (C) + 1];                    \
    if (HAS_ACT) {                                                           \
      _Pragma("unroll") for (int kt = 0; kt < 2; ++kt) {                     \
        const int t0 = ((kt * 8 + 2 * (C)) * 64 + lane) * 8;                 \
        const int t1 = ((kt * 8 + 2 * (C) + 1) * 64 + lane) * 8;             \
        const f16x8 bh0 = *(const f16x8*)&w1h[t0];                           \
        const f16x8 bl0 = *(const f16x8*)&w1l[t0];                           \
        MFMA3(a10, AH[0][kt], AL[0][kt], bh0, bl0)                           \
        MFMA3(a12, AH[1][kt], AL[1][kt], bh0, bl0)                           \
        const f16x8 bh1 = *(const f16x8*)&w1h[t1];                           \
        const f16x8 bl1 = *(const f16x8*)&w1l[t1];                           \
        MFMA3(a11, AH[0][kt], AL[0][kt], bh1, bl1)                           \
        MFMA3(a13, AH[1][kt], AL[1][kt], bh1, bl1)                           \
      }                                                                      \
    }                                                                        \
    _Pragma("unroll") for (int j = 0; j < 4; ++j) {                          \
      (BUF)[swz(r0 + j, cA)]           = fmaxf(a10[j], 0.f);                 \
      (BUF)[swz(r0 + j, 16 + cA)]      = fmaxf(a11[j], 0.f);                 \
      (BUF)[swz(16 + r0 + j, cA)]      = fmaxf(a12[j], 0.f);                 \
      (BUF)[swz(16 + r0 + j, 16 + cA)] = fmaxf(a13[j], 0.f);                 \
    }                                                                        \
  }

#define L2_CONSUME(C, BUF)                                                   \
  {                                                                          \
    const float4 va = *(const float4*)&(BUF)[swz(cA, kg)];                   \
    const float4 vb = *(const float4*)&(BUF)[swz(cA, kg + 4)];               \
    const float4 vc = *(const float4*)&(BUF)[swz(16 + cA, kg)];              \
    const float4 vd = *(const float4*)&(BUF)[swz(16 + cA, kg + 4)];          \
    f16x8 hh0, hl0, hh1, hl1;                                                \
    split44(va, vb, hh0, hl0);                                               \
    split44(vc, vd, hh1, hl1);                                               \
    _Pragma("unroll") for (int n2 = 0; n2 < 4; ++n2) {                       \
      const int tt = (((C) * 4 + n2) * 64 + lane) * 8;                       \
      const f16x8 wh = *(const f16x8*)&w2h[tt];                              \
      const f16x8 wl = *(const f16x8*)&w2l[tt];                              \
      MFMA3(a2[0][n2], hh0, hl0, wh, wl)                                     \
      MFMA3(a2[1][n2], hh1, hl1, wh, wl)                                     \
    }                                                                        \
  }

#define H2_PRODUCE(D, BUF)                                                   \
  _Pragma("unroll") for (int j = 0; j < 4; ++j) {                            \
    (BUF)[swz(r0 + j, cA)]           = fmaxf(a2[0][2 * (D)][j], 0.f);        \
    (BUF)[swz(r0 + j, 16 + cA)]      = fmaxf(a2[0][2 * (D) + 1][j], 0.f);    \
    (BUF)[swz(16 + r0 + j, cA)]      = fmaxf(a2[1][2 * (D)][j], 0.f);        \
    (BUF)[swz(16 + r0 + j, 16 + cA)] = fmaxf(a2[1][2 * (D) + 1][j], 0.f);    \
  }

#define L3_CONSUME(D, BUF, acc3)                                             \
  {                                                                          \
    const float4 va = *(const float4*)&(BUF)[swz(cA, kg)];                   \
    const float4 vb = *(const float4*)&(BUF)[swz(cA, kg + 4)];               \
    const float4 vc = *(const float4*)&(BUF)[swz(16 + cA, kg)];              \
    const float4 vd = *(const float4*)&(BUF)[swz(16 + cA, kg + 4)];          \
    f16x8 hh0, hl0, hh1, hl1;                                                \
    split44(va, vb, hh0, hl0);                                               \
    split44(vc, vd, hh1, hl1);                                               \
    _Pragma("unroll") for (int n3 = 0; n3 < 4; ++n3) {                       \
      const int tt = (((D) * 4 + n3) * 64 + lane) * 8;                       \
      const f16x8 wh = *(const f16x8*)&w3h[tt];                              \
      const f16x8 wl = *(const f16x8*)&w3l[tt];                              \
      MFMA3(acc3[0][n3], hh0, hl0, wh, wl)                                   \
      MFMA3(acc3[1][n3], hh1, hl1, wh, wl)                                   \
    }                                                                        \
  }

  // Chunk-pipelined body: produce c into alternating buf, consume c-1 under
  // c's L1 MFMAs. Consumption order (c=0..3, d=0..1) identical to R12.
#define MLP_BODY(AH, AL, HAS_ACT, acc3)                                      \
  {                                                                          \
    f32x4 a2[2][4];                                                          \
    _Pragma("unroll") for (int g = 0; g < 2; ++g)                            \
      _Pragma("unroll") for (int n2 = 0; n2 < 4; ++n2)                       \
        a2[g][n2] = (f32x4){b2r[n2], b2r[n2], b2r[n2], b2r[n2]};             \
    L1_PRODUCE(0, cb0, AH, AL, HAS_ACT)                                      \
    L1_PRODUCE(1, cb1, AH, AL, HAS_ACT)                                      \
    L2_CONSUME(0, cb0)                                                       \
    L1_PRODUCE(2, cb0, AH, AL, HAS_ACT)                                      \
    L2_CONSUME(1, cb1)                                                       \
    L1_PRODUCE(3, cb1, AH, AL, HAS_ACT)                                      \
    L2_CONSUME(2, cb0)                                                       \
    L2_CONSUME(3, cb1)                                                       \
    H2_PRODUCE(0, cb0)                                                       \
    H2_PRODUCE(1, cb1)                                                       \
    L3_CONSUME(0, cb0, acc3)                                                 \
    L3_CONSUME(1, cb1, acc3)                                                 \
  }

  // RNG fragment generation for pass PP into frag set (AH, AL).
#define GEN_RNG(PP, AH, AL)                                                  \
  {                                                                          \
    const unsigned gk0 = keys.k[2 * ((PP) - 1)];                             \
    const unsigned gk1 = keys.k[2 * ((PP) - 1) + 1];                         \
    _Pragma("unroll") for (int g = 0; g < 2; ++g) {                          \
      const unsigned base = (unsigned)(R0 + g * 16 + cA) * 64u + (unsigned)kg;\
      _Pragma("unroll") for (int kt = 0; kt < 2; ++kt) {                     \
        float v[8];                                                          \
        _Pragma("unroll") for (int e = 0; e < 8; ++e) {                      \
          unsigned o0, o1;                                                   \
          tf2x32(gk0, gk1, 0u, base + (unsigned)(kt * 32 + e), o0, o1);      \
          v[e] = u01(o0 ^ o1);                                               \
        }                                                                    \
        split44(*(const float4*)&v[0], *(const float4*)&v[4],                \
                AH[g][kt], AL[g][kt]);                                       \
      }                                                                      \
    }                                                                        \
  }

  f16x8 ah[2][2], al[2][2];

  // ---- with-actions pass FIRST -> pw -> parked in pwbuf (d_ws) ----
  {
#pragma unroll
    for (int g = 0; g < 2; ++g) {
      const float* arow = actions + (size_t)(R0 + g * 16 + cA) * 64 + kg;
#pragma unroll
      for (int kt = 0; kt < 2; ++kt) {
        const float4 va = *(const float4*)(arow + kt * 32);
        const float4 vb = *(const float4*)(arow + kt * 32 + 4);
        split44(va, vb, ah[g][kt], al[g][kt]);
      }
    }
    f32x4 pw[2][4];
#pragma unroll
    for (int g = 0; g < 2; ++g)
#pragma unroll
      for (int nt = 0; nt < 4; ++nt) pw[g][nt] = (f32x4){0.f, 0.f, 0.f, 0.f};
    MLP_BODY(ah, al, true, pw)
#pragma unroll
    for (int g = 0; g < 2; ++g)
#pragma unroll
      for (int n3 = 0; n3 < 4; ++n3)
#pragma unroll
        for (int j = 0; j < 4; ++j)
          pwbuf[(size_t)(R0 + g * 16 + r0 + j) * 64 + n3 * 16 + cA] =
              pw[g][n3][j];
  }

  // ---- passes 0..10 -> pacc; GEN(p+1) after body(p) (single frag set) ----
  f32x4 pacc[2][4];
#pragma unroll
  for (int g = 0; g < 2; ++g)
#pragma unroll
    for (int nt = 0; nt < 4; ++nt) pacc[g][nt] = (f32x4){0.f, 0.f, 0.f, 0.f};

  GEN_RNG(1, ah, al)                 // overlaps with pass 0 (no frag reads)
  MLP_BODY(ah, al, false, pacc)      // pass 0
#pragma unroll 1
  for (int p = 1; p <= 10; ++p) {
    MLP_BODY(ah, al, true, pacc)     // consumes frags(p) in L1 phase only
    if (p < 10) GEN_RNG(p + 1, ah, al)   // floats into body(p)'s MFMA shadow
  }

  // ---- epilogue: reload pw; softmax/KL per row, 16-lane shfl reductions ----
  const float inv11 = 1.0f / 11.0f;
  float b3r[4];
#pragma unroll
  for (int n3 = 0; n3 < 4; ++n3) b3r[n3] = b3[n3 * 16 + cA];

#pragma unroll
  for (int g = 0; g < 2; ++g) {
#pragma unroll
    for (int j = 0; j < 4; ++j) {
      float pwv[4], pav[4];
#pragma unroll
      for (int nt = 0; nt < 4; ++nt) {
        pwv[nt] = pwbuf[(size_t)(R0 + g * 16 + r0 + j) * 64 + nt * 16 + cA] +
                  b3r[nt];
        pav[nt] = pacc[g][nt][j] * inv11 + b3r[nt];
      }
      float mw = fmaxf(fmaxf(pwv[0], pwv[1]), fmaxf(pwv[2], pwv[3]));
      float ma = fmaxf(fmaxf(pav[0], pav[1]), fmaxf(pav[2], pav[3]));
#pragma unroll
      for (int off = 1; off < 16; off <<= 1) {
        mw = fmaxf(mw, __shfl_xor(mw, off, 64));
        ma = fmaxf(ma, __shfl_xor(ma, off, 64));
      }
      float sw = 0.f, sa = 0.f;
#pragma unroll
      for (int nt = 0; nt < 4; ++nt) {
        sw += expf(pwv[nt] - mw);
        sa += expf(pav[nt] - ma);
      }
#pragma unroll
      for (int off = 1; off < 16; off <<= 1) {
        sw += __shfl_xor(sw, off, 64);
        sa += __shfl_xor(sa, off, 64);
      }
      const float lzw = logf(sw), lza = logf(sa);
      float contrib = 0.f;
#pragma unroll
      for (int nt = 0; nt < 4; ++nt) {
        const float lq = pav[nt] - ma - lza;
        const float lp = pwv[nt] - mw - lzw;
        contrib += expf(lq) * (lq - lp);
      }
#pragma unroll
      for (int off = 1; off < 16; off <<= 1)
        contrib += __shfl_xor(contrib, off, 64);
      if (cA == 0) out[R0 + g * 16 + r0 + j] = contrib * (1.0f / 64.0f);
    }
  }
}

extern "C" void kernel_launch(void* const* d_in, const int* in_sizes, int n_in,
                              void* d_out, int out_size, void* d_ws, size_t ws_size,
                              hipStream_t stream) {
  (void)in_sizes; (void)n_in; (void)ws_size; (void)out_size;
  const float* obs     = (const float*)d_in[0];
  const float* actions = (const float*)d_in[1];
  const float* W1      = (const float*)d_in[2];
  const float* b1      = (const float*)d_in[3];
  const float* W2      = (const float*)d_in[4];
  const float* b2      = (const float*)d_in[5];
  const float* W3      = (const float*)d_in[6];
  const float* b3      = (const float*)d_in[7];

  float* pwbuf = (float*)d_ws;   // 131072 x 64 f32 = 33.5 MB

  TFKeys keys;
  for (unsigned j = 0; j < NCF; ++j) {
    unsigned o0, o1;
    tf2x32(0u, 42u, 0u, j, o0, o1);
    keys.k[2 * j]     = o0;
    keys.k[2 * j + 1] = o1;
  }

  hipLaunchKernelGGL(infl_fused, dim3(512), dim3(512), 0, stream,
                     obs, actions, W1, b1, W2, b2, W3, b3, pwbuf,
                     (float*)d_out, keys);
}